// Round 2
// baseline (1652.433 us; speedup 1.0000x reference)
//
#include <hip/hip_runtime.h>
#include <math.h>

#pragma clang fp contract(off)

#define NB 16
#define NC 80
#define NTOT 17064
#define TOPK 1000
#define NBINS 8192
#define CAP 4096
#define MAXDET 100
#define BIGCAP 262144
#define F4_PER_B 341280   // NC*NTOT/4

struct Ptrs {
    const float* lg[5];
    const float* bb[5];
    const float* ct[5];
};

__device__ __constant__ int d_f4off[6] = {0, 256000, 320000, 336000, 340160, 341280};
__device__ __constant__ int d_HW[5]    = {12800, 3200, 800, 208, 56};
__device__ __constant__ int d_lvoff[5] = {0, 12800, 16000, 16800, 17008};

__device__ __forceinline__ float sigmoidf_(float x) {
    return 1.0f / (1.0f + expf(-x));
}

__device__ __forceinline__ void level_of(int n, int& l, int& hw, int& W,
                                         int& stride, int& half, int& HW) {
    if (n < 12800)      { l = 0; hw = n;         W = 128; stride = 8;   half = 4;  HW = 12800; }
    else if (n < 16000) { l = 1; hw = n - 12800; W = 64;  stride = 16;  half = 8;  HW = 3200;  }
    else if (n < 16800) { l = 2; hw = n - 16000; W = 32;  stride = 32;  half = 16; HW = 800;   }
    else if (n < 17008) { l = 3; hw = n - 16800; W = 16;  stride = 64;  half = 32; HW = 208;   }
    else                { l = 4; hw = n - 17008; W = 8;   stride = 128; half = 64; HW = 56;    }
}

// Fused pass: linear float4 sweep of logits; LDS-private histogram; optionally
// append ALL nonzero candidates (wave-aggregated atomics) for the big-ws path.
template<bool WRITE>
__global__ void __launch_bounds__(256) k_score(Ptrs p, unsigned* hist,
                                               unsigned* cnt,
                                               unsigned long long* bigbuf) {
    __shared__ unsigned lh[NBINS];   // 32 KiB
    int b = blockIdx.y;
    int tid = threadIdx.x;
    int lane = tid & 63;
    for (int i = tid; i < NBINS; i += 256) lh[i] = 0;
    __syncthreads();
    unsigned* h = hist + (size_t)b * NBINS;

    for (int base = blockIdx.x * 256; base < F4_PER_B; base += gridDim.x * 256) {
        int i = base + tid;
        bool ok = i < F4_PER_B;
        unsigned long long keys[4];
        int nl = 0;
        if (ok) {
            int l = 0;
            if (i >= d_f4off[1])
                l = (i >= d_f4off[2]) ? ((i >= d_f4off[3]) ? ((i >= d_f4off[4]) ? 4 : 3) : 2) : 1;
            int HW = d_HW[l];
            int o = (i - d_f4off[l]) * 4;
            int c = o / HW;
            int hw = o - c * HW;
            float4 v  = *(const float4*)(p.lg[l] + (size_t)b * NC * HW + o);
            float4 ct = *(const float4*)(p.ct[l] + (size_t)b * HW + hw);
            float xs[4]  = {v.x, v.y, v.z, v.w};
            float cts[4] = {ct.x, ct.y, ct.z, ct.w};
            int nbase = d_lvoff[l] + hw;
            for (int j = 0; j < 4; ++j) {
                float x = xs[j];
                if (x > -2.95f) {                 // logit(0.05) = -2.9444
                    float cls = sigmoidf_(x);
                    if (cls > 0.05f) {
                        float cen = sigmoidf_(cts[j]);
                        float comb = cls * cen;
                        unsigned bits = __float_as_uint(comb);
                        atomicAdd(&lh[bits >> 19], 1u);
                        if (WRITE) {
                            unsigned idx = (unsigned)((nbase + j) * NC + c);
                            keys[nl++] = ((unsigned long long)bits << 32) |
                                         (0xFFFFFFFFu - idx);
                        }
                    }
                }
            }
        }
        if (WRITE) {
            int incl = nl;
            for (int off = 1; off < 64; off <<= 1) {
                int v2 = __shfl_up(incl, off);
                if (lane >= off) incl += v2;
            }
            int total = __shfl(incl, 63);
            int basep = 0;
            if (lane == 63 && total > 0)
                basep = (int)atomicAdd(&cnt[b], (unsigned)total);
            basep = __shfl(basep, 63);
            int mybase = basep + incl - nl;
            for (int k = 0; k < nl; ++k) {
                int pos = mybase + k;
                if (pos < BIGCAP)
                    bigbuf[(size_t)b * BIGCAP + pos] = keys[k];
            }
        }
    }
    __syncthreads();
    for (int i = tid; i < NBINS; i += 256) {
        unsigned v = lh[i];
        if (v) atomicAdd(&h[i], v);
    }
}

// Threshold bin T[b]: highest bin where suffix count reaches TOPK.
__global__ void k_thresh(const unsigned* hist, unsigned* T) {
    __shared__ unsigned a[256];
    __shared__ int Tf;
    int b = blockIdx.x, tid = threadIdx.x;
    if (tid == 0) Tf = 0;
    const unsigned* h = hist + (size_t)b * NBINS;
    int base = tid * 32;
    unsigned mysum = 0;
    for (int i = 0; i < 32; ++i) mysum += h[base + i];
    a[tid] = mysum;
    __syncthreads();
    for (int off = 1; off < 256; off <<= 1) {
        unsigned v = (tid + off < 256) ? a[tid + off] : 0u;
        __syncthreads();
        a[tid] += v;
        __syncthreads();
    }
    unsigned excl = a[tid] - mysum;
    if (excl < TOPK && excl + mysum >= TOPK) {
        unsigned running = excl;
        for (int bin = base + 31; bin >= base; --bin) {
            running += h[bin];
            if (running >= TOPK) { Tf = bin; break; }
        }
    }
    __syncthreads();
    if (tid == 0) T[b] = (unsigned)Tf;
}

// Big-ws path: filter the all-candidate buffer down to bins >= T.
__global__ void __launch_bounds__(256) k_filter(const unsigned* cnt, const unsigned* T,
                                                const unsigned long long* bigbuf,
                                                unsigned* cnt2, unsigned long long* sel) {
    int b = blockIdx.y, tid = threadIdx.x, lane = tid & 63;
    unsigned M = cnt[b]; if (M > BIGCAP) M = BIGCAP;
    unsigned Tb = T[b];
    for (int base = blockIdx.x * 256; base < (int)M; base += gridDim.x * 256) {
        int i = base + tid;
        unsigned long long key = 0;
        int nl = 0;
        if (i < (int)M) {
            key = bigbuf[(size_t)b * BIGCAP + i];
            if ((unsigned)(key >> 51) >= Tb) nl = 1;
        }
        int incl = nl;
        for (int off = 1; off < 64; off <<= 1) {
            int v = __shfl_up(incl, off);
            if (lane >= off) incl += v;
        }
        int total = __shfl(incl, 63);
        int basep = 0;
        if (lane == 63 && total > 0)
            basep = (int)atomicAdd(&cnt2[b], (unsigned)total);
        basep = __shfl(basep, 63);
        if (nl) {
            int pos = basep + incl - 1;
            if (pos < CAP) sel[(size_t)b * CAP + pos] = key;
        }
    }
}

// Small-ws fallback: recompute scores from logits, keep bins >= T.
__global__ void __launch_bounds__(256) k_compact2(Ptrs p, const unsigned* T,
                                                  unsigned* cnt2, unsigned long long* sel) {
    int b = blockIdx.y, tid = threadIdx.x, lane = tid & 63;
    unsigned Tb = T[b];
    for (int base = blockIdx.x * 256; base < F4_PER_B; base += gridDim.x * 256) {
        int i = base + tid;
        bool ok = i < F4_PER_B;
        unsigned long long keys[4];
        int nl = 0;
        if (ok) {
            int l = 0;
            if (i >= d_f4off[1])
                l = (i >= d_f4off[2]) ? ((i >= d_f4off[3]) ? ((i >= d_f4off[4]) ? 4 : 3) : 2) : 1;
            int HW = d_HW[l];
            int o = (i - d_f4off[l]) * 4;
            int c = o / HW;
            int hw = o - c * HW;
            float4 v  = *(const float4*)(p.lg[l] + (size_t)b * NC * HW + o);
            float4 ct = *(const float4*)(p.ct[l] + (size_t)b * HW + hw);
            float xs[4]  = {v.x, v.y, v.z, v.w};
            float cts[4] = {ct.x, ct.y, ct.z, ct.w};
            int nbase = d_lvoff[l] + hw;
            for (int j = 0; j < 4; ++j) {
                float x = xs[j];
                if (x > -2.95f) {
                    float cls = sigmoidf_(x);
                    if (cls > 0.05f) {
                        float cen = sigmoidf_(cts[j]);
                        float comb = cls * cen;
                        unsigned bits = __float_as_uint(comb);
                        if ((bits >> 19) >= Tb) {
                            unsigned idx = (unsigned)((nbase + j) * NC + c);
                            keys[nl++] = ((unsigned long long)bits << 32) |
                                         (0xFFFFFFFFu - idx);
                        }
                    }
                }
            }
        }
        int incl = nl;
        for (int off = 1; off < 64; off <<= 1) {
            int v2 = __shfl_up(incl, off);
            if (lane >= off) incl += v2;
        }
        int total = __shfl(incl, 63);
        int basep = 0;
        if (lane == 63 && total > 0)
            basep = (int)atomicAdd(&cnt2[b], (unsigned)total);
        basep = __shfl(basep, 63);
        int mybase = basep + incl - nl;
        for (int k = 0; k < nl; ++k) {
            int pos = mybase + k;
            if (pos < CAP) sel[(size_t)b * CAP + pos] = keys[k];
        }
    }
}

// Per-batch bitonic sort of CAP keys (desc; pads=0 sort last). Exact
// lax.top_k order: value desc, index asc via complemented idx low bits.
__global__ void __launch_bounds__(256) k_sort(const unsigned* cnt,
                                              const unsigned long long* buf,
                                              unsigned long long* topk) {
    __shared__ unsigned long long keys[CAP];   // 32 KiB
    int b = blockIdx.x, tid = threadIdx.x;
    unsigned M = cnt[b];
    if (M > CAP) M = CAP;
    for (int i = tid; i < CAP; i += 256)
        keys[i] = (i < (int)M) ? buf[(size_t)b * CAP + i] : 0ULL;
    __syncthreads();
    for (int k = 2; k <= CAP; k <<= 1) {
        for (int j = k >> 1; j > 0; j >>= 1) {
            for (int i = tid; i < CAP; i += 256) {
                int ixj = i ^ j;
                if (ixj > i) {
                    unsigned long long va = keys[i], vb = keys[ixj];
                    bool desc = ((i & k) == 0);
                    if (desc ? (va < vb) : (va > vb)) { keys[i] = vb; keys[ixj] = va; }
                }
            }
            __syncthreads();
        }
    }
    for (int r = tid; r < TOPK; r += 256)
        topk[(size_t)b * TOPK + r] = keys[r];
}

// Decode boxes + greedy class-aware NMS, one block per batch.
__global__ void __launch_bounds__(256) k_nms(Ptrs p, const unsigned long long* topk,
                                             const float* im_info, float* out) {
    __shared__ float nb0[TOPK], nb1[TOPK], nb2[TOPK], nb3[TOPK];
    __shared__ float area[TOPK], sc[TOPK];
    __shared__ float ox1[TOPK], oy1[TOPK], ox2[TOPK], oy2[TOPK], clsf[TOPK];
    __shared__ float rs[256];
    __shared__ int   ri[256];
    __shared__ int   pick;
    int b = blockIdx.x, tid = threadIdx.x;
    float Him = im_info[b * 2 + 0], Wim = im_info[b * 2 + 1];
    float xmax = Wim - 1.0f, ymax = Him - 1.0f;

    for (int r = tid; r < TOPK; r += 256) {
        unsigned long long key = topk[(size_t)b * TOPK + r];
        unsigned sb = (unsigned)(key >> 32);
        if (sb == 0) {
            nb0[r] = nb1[r] = nb2[r] = nb3[r] = 0.f;
            area[r] = 0.f; sc[r] = 0.f;
            ox1[r] = oy1[r] = ox2[r] = oy2[r] = 0.f; clsf[r] = 0.f;
        } else {
            unsigned idx = 0xFFFFFFFFu - (unsigned)(key & 0xFFFFFFFFu);
            float val = __uint_as_float(sb);
            int n = idx / NC, c = idx - n * NC;
            int l, hw, W, stride, half, HW;
            level_of(n, l, hw, W, stride, half, HW);
            int wx = hw % W, hy = hw / W;
            float locx = (float)(wx * stride + half);
            float locy = (float)(hy * stride + half);
            const float* bb = p.bb[l] + (size_t)b * 4 * HW + hw;
            float r0 = bb[0], r1 = bb[(size_t)HW], r2 = bb[(size_t)2 * HW], r3 = bb[(size_t)3 * HW];
            float x1 = locx - r0, y1 = locy - r1, x2 = locx + r2, y2 = locy + r3;
            x1 = fminf(fmaxf(x1, 0.f), xmax);
            y1 = fminf(fmaxf(y1, 0.f), ymax);
            x2 = fminf(fmaxf(x2, 0.f), xmax);
            y2 = fminf(fmaxf(y2, 0.f), ymax);
            float s = sqrtf(val + 1e-12f);
            float off = (float)c * 10000.0f;
            ox1[r] = x1; oy1[r] = y1; ox2[r] = x2; oy2[r] = y2; clsf[r] = (float)c;
            sc[r] = s;
            float a0 = x1 + off, a1 = y1 + off, a2 = x2 + off, a3 = y2 + off;
            nb0[r] = a0; nb1[r] = a1; nb2[r] = a2; nb3[r] = a3;
            area[r] = fmaxf(a2 - a0, 0.f) * fmaxf(a3 - a1, 0.f);
        }
    }
    __syncthreads();

    for (int it = 0; it < MAXDET; ++it) {
        float best = -__builtin_inff();
        int bi = 0x7FFFFFFF;
        for (int r = tid; r < TOPK; r += 256) {
            float s = sc[r];
            if (s > best || (s == best && r < bi)) { best = s; bi = r; }
        }
        rs[tid] = best; ri[tid] = bi;
        __syncthreads();
        for (int step = 128; step > 0; step >>= 1) {
            if (tid < step) {
                float s2 = rs[tid + step]; int i2 = ri[tid + step];
                if (s2 > rs[tid] || (s2 == rs[tid] && i2 < ri[tid])) {
                    rs[tid] = s2; ri[tid] = i2;
                }
            }
            __syncthreads();
        }
        if (tid == 0) {
            int i = ri[0];
            float s = rs[0];
            pick = i;
            float* o = out + ((size_t)b * MAXDET + it) * 6;
            if (s > 0.f) {
                o[0] = ox1[i]; o[1] = oy1[i]; o[2] = ox2[i]; o[3] = oy2[i];
                o[4] = s;      o[5] = clsf[i];
            } else {
                o[0] = 0.f; o[1] = 0.f; o[2] = 0.f; o[3] = 0.f; o[4] = 0.f; o[5] = 0.f;
            }
        }
        __syncthreads();
        int i = pick;
        float bi0 = nb0[i], bi1 = nb1[i], bi2 = nb2[i], bi3 = nb3[i], ai = area[i];
        for (int r = tid; r < TOPK; r += 256) {
            float xx1 = fmaxf(bi0, nb0[r]);
            float yy1 = fmaxf(bi1, nb1[r]);
            float xx2 = fminf(bi2, nb2[r]);
            float yy2 = fminf(bi3, nb3[r]);
            float inter = fmaxf(xx2 - xx1, 0.f) * fmaxf(yy2 - yy1, 0.f);
            float iou = inter / (((ai + area[r]) - inter) + 1e-9f);
            if (iou >= 0.6f || r == i) sc[r] = -__builtin_inff();
        }
        __syncthreads();
    }
}

extern "C" void kernel_launch(void* const* d_in, const int* in_sizes, int n_in,
                              void* d_out, int out_size, void* d_ws, size_t ws_size,
                              hipStream_t stream) {
    Ptrs p;
    for (int l = 0; l < 5; ++l) {
        p.lg[l] = (const float*)d_in[3 * l + 0];
        p.bb[l] = (const float*)d_in[3 * l + 1];
        p.ct[l] = (const float*)d_in[3 * l + 2];
    }
    const float* im_info = (const float*)d_in[15];
    float* out = (float*)d_out;

    unsigned char* w = (unsigned char*)d_ws;
    // layout: [hist 524288 | cnt 256 | cnt2 256 | T 256] (zeroed) | sel | topk | bigbuf
    unsigned* hist           = (unsigned*)(w);
    unsigned* cnt            = (unsigned*)(w + 524288);
    unsigned* cnt2           = (unsigned*)(w + 524544);
    unsigned* T              = (unsigned*)(w + 524800);
    unsigned long long* sel  = (unsigned long long*)(w + 525056);   // 16*4096*8
    unsigned long long* topk = (unsigned long long*)(w + 1049344);  // 16*1000*8
    unsigned long long* bigbuf = (unsigned long long*)(w + 1179648); // 16*262144*8

    const bool big = ws_size >= (size_t)1179648 + (size_t)NB * BIGCAP * 8;

    hipMemsetAsync(w, 0, 525056, stream);

    dim3 gscore(64, NB);
    if (big) k_score<true ><<<gscore, 256, 0, stream>>>(p, hist, cnt, bigbuf);
    else     k_score<false><<<gscore, 256, 0, stream>>>(p, hist, cnt, nullptr);

    k_thresh<<<NB, 256, 0, stream>>>(hist, T);

    if (big) k_filter<<<dim3(32, NB), 256, 0, stream>>>(cnt, T, bigbuf, cnt2, sel);
    else     k_compact2<<<dim3(64, NB), 256, 0, stream>>>(p, T, cnt2, sel);

    k_sort<<<NB, 256, 0, stream>>>(cnt2, sel, topk);
    k_nms<<<NB, 256, 0, stream>>>(p, topk, im_info, out);
}

// Round 3
// 685.663 us; speedup vs baseline: 2.4100x; 2.4100x over previous
//
#include <hip/hip_runtime.h>
#include <math.h>

#pragma clang fp contract(off)

#define NB 16
#define NC 80
#define NTOT 17064
#define TOPK 1000
#define NBINS 8192
#define CAP 4096
#define MAXDET 100
#define F4_PER_B 341280   // NC*NTOT/4

struct Ptrs {
    const float* lg[5];
    const float* bb[5];
    const float* ct[5];
};

__device__ __forceinline__ float sigmoidf_(float x) {
    return 1.0f / (1.0f + expf(-x));
}

// Immediate-constant level select (no memory LUTs — avoids per-lane constant
// gathers that serialized round 2).
__device__ __forceinline__ void f4_level(int i, int& l, int& HW, int& f4off, int& lvoff) {
    if (i < 256000)      { l = 0; HW = 12800; f4off = 0;      lvoff = 0; }
    else if (i < 320000) { l = 1; HW = 3200;  f4off = 256000; lvoff = 12800; }
    else if (i < 336000) { l = 2; HW = 800;   f4off = 320000; lvoff = 16000; }
    else if (i < 340160) { l = 3; HW = 208;   f4off = 336000; lvoff = 16800; }
    else                 { l = 4; HW = 56;    f4off = 340160; lvoff = 17008; }
}

__device__ __forceinline__ void level_of(int n, int& l, int& hw, int& W,
                                         int& stride, int& half, int& HW) {
    if (n < 12800)      { l = 0; hw = n;         W = 128; stride = 8;   half = 4;  HW = 12800; }
    else if (n < 16000) { l = 1; hw = n - 12800; W = 64;  stride = 16;  half = 8;  HW = 3200;  }
    else if (n < 16800) { l = 2; hw = n - 16000; W = 32;  stride = 32;  half = 16; HW = 800;   }
    else if (n < 17008) { l = 3; hw = n - 16800; W = 16;  stride = 64;  half = 32; HW = 208;   }
    else                { l = 4; hw = n - 17008; W = 8;   stride = 128; half = 64; HW = 56;    }
}

// Pass A: pure histogram. Linear float4 sweep, LDS-private hist, one global
// atomic per nonzero bin per block at the end. No other global atomics.
__global__ void __launch_bounds__(256) k_histA(Ptrs p, unsigned* hist) {
    __shared__ unsigned lh[NBINS];   // 32 KiB
    int b = blockIdx.y, tid = threadIdx.x;
    for (int i = tid; i < NBINS; i += 256) lh[i] = 0;
    __syncthreads();

    for (int i0 = blockIdx.x * 256; i0 < F4_PER_B; i0 += gridDim.x * 256) {
        int i = i0 + tid;
        if (i < F4_PER_B) {
            int l, HW, f4off, lvoff;
            f4_level(i, l, HW, f4off, lvoff);
            const float* lgb = p.lg[l];
            const float* ctb = p.ct[l];
            int o = (i - f4off) * 4;
            int c = o / HW;
            int hw = o - c * HW;
            float4 v  = *(const float4*)(lgb + (size_t)b * NC * HW + o);
            float4 ct = *(const float4*)(ctb + (size_t)b * HW + hw);
            float xs[4]  = {v.x, v.y, v.z, v.w};
            float cts[4] = {ct.x, ct.y, ct.z, ct.w};
#pragma unroll
            for (int j = 0; j < 4; ++j) {
                float x = xs[j];
                if (x > -2.95f) {                 // logit(0.05) = -2.9444
                    float cls = sigmoidf_(x);
                    if (cls > 0.05f) {
                        float cen = sigmoidf_(cts[j]);
                        float comb = cls * cen;
                        atomicAdd(&lh[__float_as_uint(comb) >> 19], 1u);
                    }
                }
            }
        }
    }
    __syncthreads();
    unsigned* h = hist + (size_t)b * NBINS;
    for (int i = tid; i < NBINS; i += 256) {
        unsigned v = lh[i];
        if (v) atomicAdd(&h[i], v);
    }
}

// Threshold bin T[b]: highest bin where suffix count reaches TOPK.
// LDS-staged for coalesced global reads.
__global__ void __launch_bounds__(256) k_thresh(const unsigned* hist, unsigned* T) {
    __shared__ unsigned hl[NBINS];
    __shared__ unsigned a[256];
    __shared__ int Tf;
    int b = blockIdx.x, tid = threadIdx.x;
    if (tid == 0) Tf = 0;
    const unsigned* h = hist + (size_t)b * NBINS;
    for (int i = tid; i < NBINS; i += 256) hl[i] = h[i];
    __syncthreads();
    int base = tid * 32;
    unsigned mysum = 0;
    for (int i = 0; i < 32; ++i) mysum += hl[base + i];
    a[tid] = mysum;
    __syncthreads();
    for (int off = 1; off < 256; off <<= 1) {
        unsigned v = (tid + off < 256) ? a[tid + off] : 0u;
        __syncthreads();
        a[tid] += v;
        __syncthreads();
    }
    unsigned excl = a[tid] - mysum;
    if (excl < TOPK && excl + mysum >= TOPK) {
        unsigned running = excl;
        for (int bin = base + 31; bin >= base; --bin) {
            running += hl[bin];
            if (running >= TOPK) { Tf = bin; break; }
        }
    }
    __syncthreads();
    if (tid == 0) T[b] = (unsigned)Tf;
}

// Pass B: recompute scores, compact keys with bin >= T. Ballot-aggregated
// append: register-resident, one atomic per wave-iteration that has hits.
__global__ void __launch_bounds__(256) k_compactB(Ptrs p, const unsigned* T,
                                                  unsigned* cnt2, unsigned long long* sel) {
    int b = blockIdx.y, tid = threadIdx.x, lane = tid & 63;
    unsigned Tb = T[b];
    unsigned long long ltmask = (1ULL << lane) - 1ULL;
    unsigned long long* selb = sel + (size_t)b * CAP;

    for (int i0 = blockIdx.x * 256; i0 < F4_PER_B; i0 += gridDim.x * 256) {
        int i = i0 + tid;
        bool f0 = false, f1 = false, f2 = false, f3 = false;
        unsigned long long k0 = 0, k1 = 0, k2 = 0, k3 = 0;
        if (i < F4_PER_B) {
            int l, HW, f4off, lvoff;
            f4_level(i, l, HW, f4off, lvoff);
            const float* lgb = p.lg[l];
            const float* ctb = p.ct[l];
            int o = (i - f4off) * 4;
            int c = o / HW;
            int hw = o - c * HW;
            float4 v  = *(const float4*)(lgb + (size_t)b * NC * HW + o);
            float4 ct = *(const float4*)(ctb + (size_t)b * HW + hw);
            int nb0 = lvoff + hw;
            float xs[4]  = {v.x, v.y, v.z, v.w};
            float cts[4] = {ct.x, ct.y, ct.z, ct.w};
            bool fl[4];
            unsigned long long kk[4];
#pragma unroll
            for (int j = 0; j < 4; ++j) {
                fl[j] = false; kk[j] = 0;
                float x = xs[j];
                if (x > -2.95f) {
                    float cls = sigmoidf_(x);
                    if (cls > 0.05f) {
                        float cen = sigmoidf_(cts[j]);
                        float comb = cls * cen;
                        unsigned bits = __float_as_uint(comb);
                        if ((bits >> 19) >= Tb) {
                            unsigned idx = (unsigned)((nb0 + j) * NC + c);
                            kk[j] = ((unsigned long long)bits << 32) | (0xFFFFFFFFu - idx);
                            fl[j] = true;
                        }
                    }
                }
            }
            f0 = fl[0]; f1 = fl[1]; f2 = fl[2]; f3 = fl[3];
            k0 = kk[0]; k1 = kk[1]; k2 = kk[2]; k3 = kk[3];
        }
        unsigned long long m0 = __ballot(f0);
        unsigned long long m1 = __ballot(f1);
        unsigned long long m2 = __ballot(f2);
        unsigned long long m3 = __ballot(f3);
        unsigned t0 = (unsigned)__popcll(m0), t1 = (unsigned)__popcll(m1);
        unsigned t2 = (unsigned)__popcll(m2), t3 = (unsigned)__popcll(m3);
        unsigned total = t0 + t1 + t2 + t3;
        int basep = 0;
        if (lane == 0 && total > 0)
            basep = (int)atomicAdd(&cnt2[b], total);
        basep = __shfl(basep, 0);
        if (total > 0) {
            if (f0) { int pos = basep + (int)__popcll(m0 & ltmask);                       if (pos < CAP) selb[pos] = k0; }
            if (f1) { int pos = basep + (int)t0 + (int)__popcll(m1 & ltmask);             if (pos < CAP) selb[pos] = k1; }
            if (f2) { int pos = basep + (int)(t0 + t1) + (int)__popcll(m2 & ltmask);      if (pos < CAP) selb[pos] = k2; }
            if (f3) { int pos = basep + (int)(t0 + t1 + t2) + (int)__popcll(m3 & ltmask); if (pos < CAP) selb[pos] = k3; }
        }
    }
}

// Per-batch bitonic sort of CAP keys (desc; pads=0 sort last). Exact
// lax.top_k order: value desc, index asc via complemented idx low bits.
__global__ void __launch_bounds__(256) k_sort(const unsigned* cnt,
                                              const unsigned long long* buf,
                                              unsigned long long* topk) {
    __shared__ unsigned long long keys[CAP];   // 32 KiB
    int b = blockIdx.x, tid = threadIdx.x;
    unsigned M = cnt[b];
    if (M > CAP) M = CAP;
    for (int i = tid; i < CAP; i += 256)
        keys[i] = (i < (int)M) ? buf[(size_t)b * CAP + i] : 0ULL;
    __syncthreads();
    for (int k = 2; k <= CAP; k <<= 1) {
        for (int j = k >> 1; j > 0; j >>= 1) {
            for (int i = tid; i < CAP; i += 256) {
                int ixj = i ^ j;
                if (ixj > i) {
                    unsigned long long va = keys[i], vb = keys[ixj];
                    bool desc = ((i & k) == 0);
                    if (desc ? (va < vb) : (va > vb)) { keys[i] = vb; keys[ixj] = va; }
                }
            }
            __syncthreads();
        }
    }
    for (int r = tid; r < TOPK; r += 256)
        topk[(size_t)b * TOPK + r] = keys[r];
}

// Decode boxes + greedy class-aware NMS, one block per batch.
// Fused suppress+argmax sweep with packed u64 keys; 2 barriers/iteration.
__global__ void __launch_bounds__(256) k_nms(Ptrs p, const unsigned long long* topk,
                                             const float* im_info, float* out) {
    __shared__ float nb0[TOPK], nb1[TOPK], nb2[TOPK], nb3[TOPK], area[TOPK];
    __shared__ float ox1[TOPK], oy1[TOPK], ox2[TOPK], oy2[TOPK], clsf[TOPK], osc[TOPK];
    __shared__ unsigned long long nkey[TOPK];
    __shared__ unsigned long long wbest[4];
    __shared__ int s_pick;
    __shared__ float s_b0, s_b1, s_b2, s_b3, s_a;
    int b = blockIdx.x, tid = threadIdx.x;
    float Him = im_info[b * 2 + 0], Wim = im_info[b * 2 + 1];
    float xmax = Wim - 1.0f, ymax = Him - 1.0f;

    for (int r = tid; r < TOPK; r += 256) {
        unsigned long long key = topk[(size_t)b * TOPK + r];
        unsigned sb = (unsigned)(key >> 32);
        if (sb == 0) {
            nb0[r] = nb1[r] = nb2[r] = nb3[r] = 0.f;
            area[r] = 0.f; osc[r] = 0.f;
            ox1[r] = oy1[r] = ox2[r] = oy2[r] = 0.f; clsf[r] = 0.f;
            nkey[r] = 0;
        } else {
            unsigned idx = 0xFFFFFFFFu - (unsigned)(key & 0xFFFFFFFFu);
            float val = __uint_as_float(sb);
            int n = idx / NC, c = idx - n * NC;
            int l, hw, W, stride, half, HW;
            level_of(n, l, hw, W, stride, half, HW);
            int wx = hw % W, hy = hw / W;
            float locx = (float)(wx * stride + half);
            float locy = (float)(hy * stride + half);
            const float* bb = p.bb[l] + (size_t)b * 4 * HW + hw;
            float r0 = bb[0], r1 = bb[(size_t)HW], r2 = bb[(size_t)2 * HW], r3 = bb[(size_t)3 * HW];
            float x1 = locx - r0, y1 = locy - r1, x2 = locx + r2, y2 = locy + r3;
            x1 = fminf(fmaxf(x1, 0.f), xmax);
            y1 = fminf(fmaxf(y1, 0.f), ymax);
            x2 = fminf(fmaxf(x2, 0.f), xmax);
            y2 = fminf(fmaxf(y2, 0.f), ymax);
            float s = sqrtf(val + 1e-12f);
            float off = (float)c * 10000.0f;
            ox1[r] = x1; oy1[r] = y1; ox2[r] = x2; oy2[r] = y2; clsf[r] = (float)c;
            osc[r] = s;
            float a0 = x1 + off, a1 = y1 + off, a2 = x2 + off, a3 = y2 + off;
            nb0[r] = a0; nb1[r] = a1; nb2[r] = a2; nb3[r] = a3;
            area[r] = fmaxf(a2 - a0, 0.f) * fmaxf(a3 - a1, 0.f);
            // (sb<<10)|(1023-r): argmax by (score desc, rank asc) — rank asc
            // == index asc because k_sort already ordered by (val desc, idx asc)
            nkey[r] = ((unsigned long long)sb << 10) | (unsigned long long)(1023 - r);
        }
    }
    if (tid == 0) s_pick = -1;
    __syncthreads();

    for (int it = 0; it < MAXDET; ++it) {
        int pk = s_pick;
        float pb0 = s_b0, pb1 = s_b1, pb2 = s_b2, pb3 = s_b3, pa = s_a;
        unsigned long long lbest = 0;
        for (int r = tid; r < TOPK; r += 256) {
            unsigned long long k = nkey[r];
            if (k) {
                if (pk >= 0) {
                    float xx1 = fmaxf(pb0, nb0[r]);
                    float yy1 = fmaxf(pb1, nb1[r]);
                    float xx2 = fminf(pb2, nb2[r]);
                    float yy2 = fminf(pb3, nb3[r]);
                    float inter = fmaxf(xx2 - xx1, 0.f) * fmaxf(yy2 - yy1, 0.f);
                    float iou = inter / (((pa + area[r]) - inter) + 1e-9f);
                    if (iou >= 0.6f || r == pk) { k = 0; nkey[r] = 0; }
                }
                if (k > lbest) lbest = k;
            }
        }
        for (int off = 32; off > 0; off >>= 1) {
            unsigned long long o = __shfl_down(lbest, off);
            if (o > lbest) lbest = o;
        }
        if ((tid & 63) == 0) wbest[tid >> 6] = lbest;
        __syncthreads();
        if (tid == 0) {
            unsigned long long bk = wbest[0];
            if (wbest[1] > bk) bk = wbest[1];
            if (wbest[2] > bk) bk = wbest[2];
            if (wbest[3] > bk) bk = wbest[3];
            float* o6 = out + ((size_t)b * MAXDET + it) * 6;
            if (bk) {
                int r = 1023 - (int)(bk & 1023ULL);
                o6[0] = ox1[r]; o6[1] = oy1[r]; o6[2] = ox2[r]; o6[3] = oy2[r];
                o6[4] = osc[r]; o6[5] = clsf[r];
                s_pick = r;
                s_b0 = nb0[r]; s_b1 = nb1[r]; s_b2 = nb2[r]; s_b3 = nb3[r]; s_a = area[r];
            } else {
                o6[0] = 0.f; o6[1] = 0.f; o6[2] = 0.f; o6[3] = 0.f; o6[4] = 0.f; o6[5] = 0.f;
                s_pick = -1;
            }
        }
        __syncthreads();
    }
}

extern "C" void kernel_launch(void* const* d_in, const int* in_sizes, int n_in,
                              void* d_out, int out_size, void* d_ws, size_t ws_size,
                              hipStream_t stream) {
    Ptrs p;
    for (int l = 0; l < 5; ++l) {
        p.lg[l] = (const float*)d_in[3 * l + 0];
        p.bb[l] = (const float*)d_in[3 * l + 1];
        p.ct[l] = (const float*)d_in[3 * l + 2];
    }
    const float* im_info = (const float*)d_in[15];
    float* out = (float*)d_out;

    unsigned char* w = (unsigned char*)d_ws;
    // layout: [hist 524288 | cnt2 256 | T 256] (zeroed) | sel | topk
    unsigned* hist           = (unsigned*)(w);
    unsigned* cnt2           = (unsigned*)(w + 524288);
    unsigned* T              = (unsigned*)(w + 524544);
    unsigned long long* sel  = (unsigned long long*)(w + 524800);   // 16*4096*8
    unsigned long long* topk = (unsigned long long*)(w + 1049088);  // 16*1000*8

    hipMemsetAsync(w, 0, 524800, stream);

    k_histA<<<dim3(80, NB), 256, 0, stream>>>(p, hist);
    k_thresh<<<NB, 256, 0, stream>>>(hist, T);
    k_compactB<<<dim3(128, NB), 256, 0, stream>>>(p, T, cnt2, sel);
    k_sort<<<NB, 256, 0, stream>>>(cnt2, sel, topk);
    k_nms<<<NB, 256, 0, stream>>>(p, topk, im_info, out);
}

// Round 4
// 515.705 us; speedup vs baseline: 3.2042x; 1.3296x over previous
//
#include <hip/hip_runtime.h>
#include <math.h>

#pragma clang fp contract(off)

#define NB 16
#define NC 80
#define NTOT 17064
#define TOPK 1000
#define NBINS 8192
#define CAP 4096
#define MAXDET 100
#define NREP 4           // histogram replicas (spread flush atomics)
#define CNTSTRIDE 64     // u32 stride between per-batch counters = 256 B

struct Ptrs {
    const float* lg[5];
    const float* bb[5];
    const float* ct[5];
};

__device__ __forceinline__ void level_of(int n, int& l, int& hw, int& W,
                                         int& stride, int& half, int& HW) {
    if (n < 12800)      { l = 0; hw = n;         W = 128; stride = 8;   half = 4;  HW = 12800; }
    else if (n < 16000) { l = 1; hw = n - 12800; W = 64;  stride = 16;  half = 8;  HW = 3200;  }
    else if (n < 16800) { l = 2; hw = n - 16000; W = 32;  stride = 32;  half = 16; HW = 800;   }
    else if (n < 17008) { l = 3; hw = n - 16800; W = 16;  stride = 64;  half = 32; HW = 208;   }
    else                { l = 4; hw = n - 17008; W = 8;   stride = 128; half = 64; HW = 56;    }
}

// ---------------- histogram sweep (per-level, compile-time constants) -------
template<int HW4, int NF4>
__device__ __forceinline__ void hist_level(const float* lgb, const float* ctb,
                                           int tid, int bx, int gx, unsigned* lh) {
    for (int i0 = bx * 256; i0 < NF4; i0 += gx * 256) {
        int i = i0 + tid;
        if (i < NF4) {
            int c   = i / HW4;            // constant divisor -> magic mul
            int hwf = i - c * HW4;
            float4 v  = *(const float4*)(lgb + c * (HW4 * 4) + hwf * 4);
            float4 cv = *(const float4*)(ctb + hwf * 4);
            float xs[4] = {v.x, v.y, v.z, v.w};
            float cs[4] = {cv.x, cv.y, cv.z, cv.w};
#pragma unroll
            for (int j = 0; j < 4; ++j) {
                float x = xs[j];
                if (x > -2.95f) {                 // logit(0.05) = -2.9444
                    float cls = 1.0f / (1.0f + expf(-x));
                    if (cls > 0.05f) {
                        float cen = 1.0f / (1.0f + expf(-cs[j]));
                        float comb = cls * cen;
                        atomicAdd(&lh[__float_as_uint(comb) >> 19], 1u);
                    }
                }
            }
        }
    }
}

__global__ void __launch_bounds__(256) k_histA(Ptrs p, unsigned* hist) {
    __shared__ unsigned lh[NBINS];   // 32 KiB
    int b = blockIdx.y, tid = threadIdx.x, bx = blockIdx.x, gx = gridDim.x;
    for (int i = tid; i < NBINS; i += 256) lh[i] = 0;
    __syncthreads();

    hist_level<3200, 256000>(p.lg[0] + (size_t)b * NC * 12800, p.ct[0] + (size_t)b * 12800, tid, bx, gx, lh);
    hist_level< 800,  64000>(p.lg[1] + (size_t)b * NC * 3200,  p.ct[1] + (size_t)b * 3200,  tid, bx, gx, lh);
    hist_level< 200,  16000>(p.lg[2] + (size_t)b * NC * 800,   p.ct[2] + (size_t)b * 800,   tid, bx, gx, lh);
    hist_level<  52,   4160>(p.lg[3] + (size_t)b * NC * 208,   p.ct[3] + (size_t)b * 208,   tid, bx, gx, lh);
    hist_level<  14,   1120>(p.lg[4] + (size_t)b * NC * 56,    p.ct[4] + (size_t)b * 56,    tid, bx, gx, lh);

    __syncthreads();
    unsigned* h = hist + ((size_t)(bx & (NREP - 1)) * NB + b) * NBINS;
    for (int i = tid; i < NBINS; i += 256) {
        unsigned v = lh[i];
        if (v) atomicAdd(&h[i], v);
    }
}

// ---------------- threshold: highest bin with suffix count >= TOPK ----------
__global__ void __launch_bounds__(256) k_thresh(const unsigned* hist, unsigned* T) {
    __shared__ unsigned hl[NBINS];
    __shared__ unsigned a[256];
    __shared__ int Tf;
    int b = blockIdx.x, tid = threadIdx.x;
    if (tid == 0) Tf = 0;
    for (int i = tid; i < NBINS; i += 256) {
        unsigned s = 0;
        for (int r = 0; r < NREP; ++r)
            s += hist[((size_t)r * NB + b) * NBINS + i];
        hl[i] = s;
    }
    __syncthreads();
    int base = tid * 32;
    unsigned mysum = 0;
    for (int i = 0; i < 32; ++i) mysum += hl[base + i];
    a[tid] = mysum;
    __syncthreads();
    for (int off = 1; off < 256; off <<= 1) {
        unsigned v = (tid + off < 256) ? a[tid + off] : 0u;
        __syncthreads();
        a[tid] += v;
        __syncthreads();
    }
    unsigned excl = a[tid] - mysum;
    if (excl < TOPK && excl + mysum >= TOPK) {
        unsigned running = excl;
        for (int bin = base + 31; bin >= base; --bin) {
            running += hl[bin];
            if (running >= TOPK) { Tf = bin; break; }
        }
    }
    __syncthreads();
    if (tid == 0) T[b] = (unsigned)Tf;
}

// ---------------- compact sweep (per-level, ballot-aggregated) --------------
template<int HW4, int NF4, int LVOFF>
__device__ __forceinline__ void compact_level(const float* lgb, const float* ctb,
        int tid, int lane, int bx, int gx, unsigned Tb, float xpre,
        unsigned* cntb, unsigned long long* selb, unsigned long long ltmask) {
    for (int i0 = bx * 256; i0 < NF4; i0 += gx * 256) {
        int i = i0 + tid;
        bool f0 = false, f1 = false, f2 = false, f3 = false;
        unsigned long long k0 = 0, k1 = 0, k2 = 0, k3 = 0;
        if (i < NF4) {
            int c   = i / HW4;
            int hwf = i - c * HW4;
            float4 v = *(const float4*)(lgb + c * (HW4 * 4) + hwf * 4);
            if (v.x > xpre || v.y > xpre || v.z > xpre || v.w > xpre) {
                float4 cv = *(const float4*)(ctb + hwf * 4);
                int nbase = LVOFF + hwf * 4;
                float xs[4] = {v.x, v.y, v.z, v.w};
                float cs[4] = {cv.x, cv.y, cv.z, cv.w};
                bool fl[4]; unsigned long long kk[4];
#pragma unroll
                for (int j = 0; j < 4; ++j) {
                    fl[j] = false; kk[j] = 0;
                    float x = xs[j];
                    if (x > xpre) {
                        float cls = 1.0f / (1.0f + expf(-x));
                        if (cls > 0.05f) {
                            float cen = 1.0f / (1.0f + expf(-cs[j]));
                            float comb = cls * cen;
                            unsigned bits = __float_as_uint(comb);
                            if ((bits >> 19) >= Tb) {
                                unsigned idx = (unsigned)((nbase + j) * NC + c);
                                kk[j] = ((unsigned long long)bits << 32) | (0xFFFFFFFFu - idx);
                                fl[j] = true;
                            }
                        }
                    }
                }
                f0 = fl[0]; f1 = fl[1]; f2 = fl[2]; f3 = fl[3];
                k0 = kk[0]; k1 = kk[1]; k2 = kk[2]; k3 = kk[3];
            }
        }
        unsigned long long m0 = __ballot(f0);
        unsigned long long m1 = __ballot(f1);
        unsigned long long m2 = __ballot(f2);
        unsigned long long m3 = __ballot(f3);
        if ((m0 | m1 | m2 | m3) == 0ULL) continue;   // wave-uniform skip
        unsigned t0 = (unsigned)__popcll(m0), t1 = (unsigned)__popcll(m1);
        unsigned t2 = (unsigned)__popcll(m2), t3 = (unsigned)__popcll(m3);
        unsigned total = t0 + t1 + t2 + t3;
        int basep = 0;
        if (lane == 0) basep = (int)atomicAdd(cntb, total);
        basep = __shfl(basep, 0);
        if (f0) { int pos = basep + (int)__popcll(m0 & ltmask);                       if (pos < CAP) selb[pos] = k0; }
        if (f1) { int pos = basep + (int)t0 + (int)__popcll(m1 & ltmask);             if (pos < CAP) selb[pos] = k1; }
        if (f2) { int pos = basep + (int)(t0 + t1) + (int)__popcll(m2 & ltmask);      if (pos < CAP) selb[pos] = k2; }
        if (f3) { int pos = basep + (int)(t0 + t1 + t2) + (int)__popcll(m3 & ltmask); if (pos < CAP) selb[pos] = k3; }
    }
}

__global__ void __launch_bounds__(256) k_compactB(Ptrs p, const unsigned* T,
                                                  unsigned* cnt2, unsigned long long* sel) {
    int b = blockIdx.y, tid = threadIdx.x, lane = tid & 63;
    int bx = blockIdx.x, gx = gridDim.x;
    unsigned Tb = T[b];
    // logit-space prefilter: bin >= T  =>  comb >= m  =>  cls > m (cen < 1)
    //  =>  x > logit(m). 0.01 margin absorbs logf rounding; exact checks follow.
    float m = __uint_as_float(Tb << 19);
    float xpre = -2.95f;
    if (m > 1e-37f && m < 1.0f) {
        float lm = logf(m / (1.0f - m)) - 0.01f;
        if (lm > xpre) xpre = lm;
    }
    unsigned long long ltmask = (1ULL << lane) - 1ULL;
    unsigned* cntb = cnt2 + (size_t)b * CNTSTRIDE;
    unsigned long long* selb = sel + (size_t)b * CAP;

    compact_level<3200, 256000,     0>(p.lg[0] + (size_t)b * NC * 12800, p.ct[0] + (size_t)b * 12800, tid, lane, bx, gx, Tb, xpre, cntb, selb, ltmask);
    compact_level< 800,  64000, 12800>(p.lg[1] + (size_t)b * NC * 3200,  p.ct[1] + (size_t)b * 3200,  tid, lane, bx, gx, Tb, xpre, cntb, selb, ltmask);
    compact_level< 200,  16000, 16000>(p.lg[2] + (size_t)b * NC * 800,   p.ct[2] + (size_t)b * 800,   tid, lane, bx, gx, Tb, xpre, cntb, selb, ltmask);
    compact_level<  52,   4160, 16800>(p.lg[3] + (size_t)b * NC * 208,   p.ct[3] + (size_t)b * 208,   tid, lane, bx, gx, Tb, xpre, cntb, selb, ltmask);
    compact_level<  14,   1120, 17008>(p.lg[4] + (size_t)b * NC * 56,    p.ct[4] + (size_t)b * 56,    tid, lane, bx, gx, Tb, xpre, cntb, selb, ltmask);
}

// ---------------- per-batch bitonic sort of CAP keys ------------------------
__global__ void __launch_bounds__(256) k_sort(const unsigned* cnt,
                                              const unsigned long long* buf,
                                              unsigned long long* topk) {
    __shared__ unsigned long long keys[CAP];   // 32 KiB
    int b = blockIdx.x, tid = threadIdx.x;
    unsigned M = cnt[(size_t)b * CNTSTRIDE];
    if (M > CAP) M = CAP;
    for (int i = tid; i < CAP; i += 256)
        keys[i] = (i < (int)M) ? buf[(size_t)b * CAP + i] : 0ULL;
    __syncthreads();
    for (int k = 2; k <= CAP; k <<= 1) {
        for (int j = k >> 1; j > 0; j >>= 1) {
            for (int i = tid; i < CAP; i += 256) {
                int ixj = i ^ j;
                if (ixj > i) {
                    unsigned long long va = keys[i], vb = keys[ixj];
                    bool desc = ((i & k) == 0);
                    if (desc ? (va < vb) : (va > vb)) { keys[i] = vb; keys[ixj] = va; }
                }
            }
            __syncthreads();
        }
    }
    for (int r = tid; r < TOPK; r += 256)
        topk[(size_t)b * TOPK + r] = keys[r];
}

// ---------------- decode + greedy class-aware NMS ---------------------------
__global__ void __launch_bounds__(256) k_nms(Ptrs p, const unsigned long long* topk,
                                             const float* im_info, float* out) {
    __shared__ float4 nbx[TOPK];               // offset box (x1,y1,x2,y2)
    __shared__ float  sarea[TOPK];
    __shared__ unsigned long long nkey[TOPK];
    __shared__ float4 obox[TOPK];              // output box
    __shared__ float2 oscl[TOPK];              // (score, class)
    __shared__ unsigned long long wbest[4];
    __shared__ int s_pick;
    __shared__ float4 s_pb;
    __shared__ float s_pa;
    int b = blockIdx.x, tid = threadIdx.x;
    float Him = im_info[b * 2 + 0], Wim = im_info[b * 2 + 1];
    float xmax = Wim - 1.0f, ymax = Him - 1.0f;

    for (int r = tid; r < TOPK; r += 256) {
        unsigned long long key = topk[(size_t)b * TOPK + r];
        unsigned sb = (unsigned)(key >> 32);
        if (sb == 0) {
            nbx[r] = make_float4(0.f, 0.f, 0.f, 0.f);
            sarea[r] = 0.f; nkey[r] = 0;
            obox[r] = make_float4(0.f, 0.f, 0.f, 0.f);
            oscl[r] = make_float2(0.f, 0.f);
        } else {
            unsigned idx = 0xFFFFFFFFu - (unsigned)(key & 0xFFFFFFFFu);
            float val = __uint_as_float(sb);
            int n = idx / NC, c = idx - n * NC;
            int l, hw, W, stride, half, HW;
            level_of(n, l, hw, W, stride, half, HW);
            int wx = hw % W, hy = hw / W;
            float locx = (float)(wx * stride + half);
            float locy = (float)(hy * stride + half);
            const float* bb = p.bb[l] + (size_t)b * 4 * HW + hw;
            float r0 = bb[0], r1 = bb[(size_t)HW], r2 = bb[(size_t)2 * HW], r3 = bb[(size_t)3 * HW];
            float x1 = locx - r0, y1 = locy - r1, x2 = locx + r2, y2 = locy + r3;
            x1 = fminf(fmaxf(x1, 0.f), xmax);
            y1 = fminf(fmaxf(y1, 0.f), ymax);
            x2 = fminf(fmaxf(x2, 0.f), xmax);
            y2 = fminf(fmaxf(y2, 0.f), ymax);
            float s = sqrtf(val + 1e-12f);
            float off = (float)c * 10000.0f;
            obox[r] = make_float4(x1, y1, x2, y2);
            oscl[r] = make_float2(s, (float)c);
            float a0 = x1 + off, a1 = y1 + off, a2 = x2 + off, a3 = y2 + off;
            nbx[r] = make_float4(a0, a1, a2, a3);
            sarea[r] = fmaxf(a2 - a0, 0.f) * fmaxf(a3 - a1, 0.f);
            // (sb<<10)|(1023-r): argmax by (score desc, rank asc); rank order
            // equals index order because k_sort sorted by (val desc, idx asc).
            nkey[r] = ((unsigned long long)sb << 10) | (unsigned long long)(1023 - r);
        }
    }
    if (tid == 0) s_pick = -1;
    __syncthreads();

    for (int it = 0; it < MAXDET; ++it) {
        int pk = s_pick;
        float4 pb = s_pb;
        float pa = s_pa;
        unsigned long long lbest = 0;
        for (int r = tid; r < TOPK; r += 256) {
            unsigned long long k = nkey[r];
            if (k) {
                if (pk >= 0) {
                    float4 nb = nbx[r];
                    float xx1 = fmaxf(pb.x, nb.x);
                    float yy1 = fmaxf(pb.y, nb.y);
                    float xx2 = fminf(pb.z, nb.z);
                    float yy2 = fminf(pb.w, nb.w);
                    float inter = fmaxf(xx2 - xx1, 0.f) * fmaxf(yy2 - yy1, 0.f);
                    float iou = inter / (((pa + sarea[r]) - inter) + 1e-9f);
                    if (iou >= 0.6f || r == pk) { k = 0; nkey[r] = 0; }
                }
                if (k > lbest) lbest = k;
            }
        }
        for (int off = 32; off > 0; off >>= 1) {
            unsigned long long o = __shfl_down(lbest, off);
            if (o > lbest) lbest = o;
        }
        if ((tid & 63) == 0) wbest[tid >> 6] = lbest;
        __syncthreads();
        if (tid == 0) {
            unsigned long long bk = wbest[0];
            if (wbest[1] > bk) bk = wbest[1];
            if (wbest[2] > bk) bk = wbest[2];
            if (wbest[3] > bk) bk = wbest[3];
            float* o6 = out + ((size_t)b * MAXDET + it) * 6;
            if (bk) {
                int r = 1023 - (int)(bk & 1023ULL);
                float4 ob = obox[r]; float2 sc2 = oscl[r];
                o6[0] = ob.x; o6[1] = ob.y; o6[2] = ob.z; o6[3] = ob.w;
                o6[4] = sc2.x; o6[5] = sc2.y;
                s_pick = r; s_pb = nbx[r]; s_pa = sarea[r];
            } else {
                o6[0] = 0.f; o6[1] = 0.f; o6[2] = 0.f;
                o6[3] = 0.f; o6[4] = 0.f; o6[5] = 0.f;
                s_pick = -1;
            }
        }
        __syncthreads();
    }
}

extern "C" void kernel_launch(void* const* d_in, const int* in_sizes, int n_in,
                              void* d_out, int out_size, void* d_ws, size_t ws_size,
                              hipStream_t stream) {
    Ptrs p;
    for (int l = 0; l < 5; ++l) {
        p.lg[l] = (const float*)d_in[3 * l + 0];
        p.bb[l] = (const float*)d_in[3 * l + 1];
        p.ct[l] = (const float*)d_in[3 * l + 2];
    }
    const float* im_info = (const float*)d_in[15];
    float* out = (float*)d_out;

    unsigned char* w = (unsigned char*)d_ws;
    // layout: [hist 4*16*32KB = 2 MiB | cnt2 16*256B | T 256B] zeroed, then sel, topk
    unsigned* hist           = (unsigned*)(w);                    // 2097152 B
    unsigned* cnt2           = (unsigned*)(w + 2097152);          // 4096 B (padded)
    unsigned* T              = (unsigned*)(w + 2101248);          // 256 B
    unsigned long long* sel  = (unsigned long long*)(w + 2101504); // 16*4096*8
    unsigned long long* topk = (unsigned long long*)(w + 2625792); // 16*1000*8

    hipMemsetAsync(w, 0, 2101248, stream);

    k_histA<<<dim3(64, NB), 256, 0, stream>>>(p, hist);
    k_thresh<<<NB, 256, 0, stream>>>(hist, T);
    k_compactB<<<dim3(128, NB), 256, 0, stream>>>(p, T, cnt2, sel);
    k_sort<<<NB, 256, 0, stream>>>(cnt2, sel, topk);
    k_nms<<<NB, 256, 0, stream>>>(p, topk, im_info, out);
}

// Round 5
// 289.002 us; speedup vs baseline: 5.7177x; 1.7844x over previous
//
#include <hip/hip_runtime.h>
#include <math.h>

#pragma clang fp contract(off)

#define NB 16
#define NC 80
#define NTOT 17064
#define TOPK 1000
#define NBINS 8192
#define CAP 4096
#define MAXDET 100
#define NREP 4           // histogram replicas (spread flush atomics)
#define CNTSTRIDE 64     // u32 stride between per-batch counters = 256 B

struct Ptrs {
    const float* lg[5];
    const float* bb[5];
    const float* ct[5];
};

__device__ __forceinline__ void level_of(int n, int& l, int& hw, int& W,
                                         int& stride, int& half, int& HW) {
    if (n < 12800)      { l = 0; hw = n;         W = 128; stride = 8;   half = 4;  HW = 12800; }
    else if (n < 16000) { l = 1; hw = n - 12800; W = 64;  stride = 16;  half = 8;  HW = 3200;  }
    else if (n < 16800) { l = 2; hw = n - 16000; W = 32;  stride = 32;  half = 16; HW = 800;   }
    else if (n < 17008) { l = 3; hw = n - 16800; W = 16;  stride = 64;  half = 32; HW = 208;   }
    else                { l = 4; hw = n - 17008; W = 8;   stride = 128; half = 64; HW = 56;    }
}

// ---------------- histogram sweep (per-level, compile-time constants) -------
template<int HW4, int NF4>
__device__ __forceinline__ void hist_level(const float* lgb, const float* ctb,
                                           int tid, int bx, int gx, unsigned* lh) {
    for (int i0 = bx * 256; i0 < NF4; i0 += gx * 256) {
        int i = i0 + tid;
        if (i < NF4) {
            int c   = i / HW4;            // constant divisor -> magic mul
            int hwf = i - c * HW4;
            float4 v  = *(const float4*)(lgb + c * (HW4 * 4) + hwf * 4);
            float4 cv = *(const float4*)(ctb + hwf * 4);
            float xs[4] = {v.x, v.y, v.z, v.w};
            float cs[4] = {cv.x, cv.y, cv.z, cv.w};
#pragma unroll
            for (int j = 0; j < 4; ++j) {
                float x = xs[j];
                if (x > -2.95f) {                 // logit(0.05) = -2.9444
                    float cls = 1.0f / (1.0f + expf(-x));
                    if (cls > 0.05f) {
                        float cen = 1.0f / (1.0f + expf(-cs[j]));
                        float comb = cls * cen;
                        atomicAdd(&lh[__float_as_uint(comb) >> 19], 1u);
                    }
                }
            }
        }
    }
}

__global__ void __launch_bounds__(256) k_histA(Ptrs p, unsigned* hist) {
    __shared__ unsigned lh[NBINS];   // 32 KiB
    int b = blockIdx.y, tid = threadIdx.x, bx = blockIdx.x, gx = gridDim.x;
    for (int i = tid; i < NBINS; i += 256) lh[i] = 0;
    __syncthreads();

    hist_level<3200, 256000>(p.lg[0] + (size_t)b * NC * 12800, p.ct[0] + (size_t)b * 12800, tid, bx, gx, lh);
    hist_level< 800,  64000>(p.lg[1] + (size_t)b * NC * 3200,  p.ct[1] + (size_t)b * 3200,  tid, bx, gx, lh);
    hist_level< 200,  16000>(p.lg[2] + (size_t)b * NC * 800,   p.ct[2] + (size_t)b * 800,   tid, bx, gx, lh);
    hist_level<  52,   4160>(p.lg[3] + (size_t)b * NC * 208,   p.ct[3] + (size_t)b * 208,   tid, bx, gx, lh);
    hist_level<  14,   1120>(p.lg[4] + (size_t)b * NC * 56,    p.ct[4] + (size_t)b * 56,    tid, bx, gx, lh);

    __syncthreads();
    unsigned* h = hist + ((size_t)(bx & (NREP - 1)) * NB + b) * NBINS;
    for (int i = tid; i < NBINS; i += 256) {
        unsigned v = lh[i];
        if (v) atomicAdd(&h[i], v);
    }
}

// ---------------- threshold: highest bin with suffix count >= TOPK ----------
__global__ void __launch_bounds__(1024) k_thresh(const unsigned* hist, unsigned* T) {
    __shared__ unsigned hl[NBINS];
    __shared__ unsigned a[1024];
    __shared__ int Tf;
    int b = blockIdx.x, tid = threadIdx.x;
    if (tid == 0) Tf = 0;
    for (int i = tid; i < NBINS; i += 1024) {
        unsigned s = 0;
        for (int r = 0; r < NREP; ++r)
            s += hist[((size_t)r * NB + b) * NBINS + i];
        hl[i] = s;
    }
    __syncthreads();
    int base = tid * 8;
    unsigned mysum = 0;
#pragma unroll
    for (int i = 0; i < 8; ++i) mysum += hl[base + i];
    a[tid] = mysum;
    __syncthreads();
    for (int off = 1; off < 1024; off <<= 1) {
        unsigned v = (tid + off < 1024) ? a[tid + off] : 0u;
        __syncthreads();
        a[tid] += v;
        __syncthreads();
    }
    unsigned excl = a[tid] - mysum;   // count in all higher chunks
    if (excl < TOPK && excl + mysum >= TOPK) {
        unsigned running = excl;
        for (int bin = base + 7; bin >= base; --bin) {
            running += hl[bin];
            if (running >= TOPK) { Tf = bin; break; }
        }
    }
    __syncthreads();
    if (tid == 0) T[b] = (unsigned)Tf;
}

// ---------------- compact sweep (per-level, ballot-aggregated) --------------
template<int HW4, int NF4, int LVOFF>
__device__ __forceinline__ void compact_level(const float* lgb, const float* ctb,
        int tid, int lane, int bx, int gx, unsigned Tb, float xpre,
        unsigned* cntb, unsigned long long* selb, unsigned long long ltmask) {
    for (int i0 = bx * 256; i0 < NF4; i0 += gx * 256) {
        int i = i0 + tid;
        bool f0 = false, f1 = false, f2 = false, f3 = false;
        unsigned long long k0 = 0, k1 = 0, k2 = 0, k3 = 0;
        if (i < NF4) {
            int c   = i / HW4;
            int hwf = i - c * HW4;
            float4 v = *(const float4*)(lgb + c * (HW4 * 4) + hwf * 4);
            if (v.x > xpre || v.y > xpre || v.z > xpre || v.w > xpre) {
                float4 cv = *(const float4*)(ctb + hwf * 4);
                int nbase = LVOFF + hwf * 4;
                float xs[4] = {v.x, v.y, v.z, v.w};
                float cs[4] = {cv.x, cv.y, cv.z, cv.w};
                bool fl[4]; unsigned long long kk[4];
#pragma unroll
                for (int j = 0; j < 4; ++j) {
                    fl[j] = false; kk[j] = 0;
                    float x = xs[j];
                    if (x > xpre) {
                        float cls = 1.0f / (1.0f + expf(-x));
                        if (cls > 0.05f) {
                            float cen = 1.0f / (1.0f + expf(-cs[j]));
                            float comb = cls * cen;
                            unsigned bits = __float_as_uint(comb);
                            if ((bits >> 19) >= Tb) {
                                unsigned idx = (unsigned)((nbase + j) * NC + c);
                                kk[j] = ((unsigned long long)bits << 32) | (0xFFFFFFFFu - idx);
                                fl[j] = true;
                            }
                        }
                    }
                }
                f0 = fl[0]; f1 = fl[1]; f2 = fl[2]; f3 = fl[3];
                k0 = kk[0]; k1 = kk[1]; k2 = kk[2]; k3 = kk[3];
            }
        }
        unsigned long long m0 = __ballot(f0);
        unsigned long long m1 = __ballot(f1);
        unsigned long long m2 = __ballot(f2);
        unsigned long long m3 = __ballot(f3);
        if ((m0 | m1 | m2 | m3) == 0ULL) continue;   // wave-uniform skip
        unsigned t0 = (unsigned)__popcll(m0), t1 = (unsigned)__popcll(m1);
        unsigned t2 = (unsigned)__popcll(m2), t3 = (unsigned)__popcll(m3);
        unsigned total = t0 + t1 + t2 + t3;
        int basep = 0;
        if (lane == 0) basep = (int)atomicAdd(cntb, total);
        basep = __shfl(basep, 0);
        if (f0) { int pos = basep + (int)__popcll(m0 & ltmask);                       if (pos < CAP) selb[pos] = k0; }
        if (f1) { int pos = basep + (int)t0 + (int)__popcll(m1 & ltmask);             if (pos < CAP) selb[pos] = k1; }
        if (f2) { int pos = basep + (int)(t0 + t1) + (int)__popcll(m2 & ltmask);      if (pos < CAP) selb[pos] = k2; }
        if (f3) { int pos = basep + (int)(t0 + t1 + t2) + (int)__popcll(m3 & ltmask); if (pos < CAP) selb[pos] = k3; }
    }
}

__global__ void __launch_bounds__(256) k_compactB(Ptrs p, const unsigned* T,
                                                  unsigned* cnt2, unsigned long long* sel) {
    int b = blockIdx.y, tid = threadIdx.x, lane = tid & 63;
    int bx = blockIdx.x, gx = gridDim.x;
    unsigned Tb = T[b];
    // logit-space prefilter: bin >= T  =>  comb >= m  =>  cls > m (cen < 1)
    //  =>  x > logit(m). 0.01 margin absorbs logf rounding; exact checks follow.
    float m = __uint_as_float(Tb << 19);
    float xpre = -2.95f;
    if (m > 1e-37f && m < 1.0f) {
        float lm = logf(m / (1.0f - m)) - 0.01f;
        if (lm > xpre) xpre = lm;
    }
    unsigned long long ltmask = (1ULL << lane) - 1ULL;
    unsigned* cntb = cnt2 + (size_t)b * CNTSTRIDE;
    unsigned long long* selb = sel + (size_t)b * CAP;

    compact_level<3200, 256000,     0>(p.lg[0] + (size_t)b * NC * 12800, p.ct[0] + (size_t)b * 12800, tid, lane, bx, gx, Tb, xpre, cntb, selb, ltmask);
    compact_level< 800,  64000, 12800>(p.lg[1] + (size_t)b * NC * 3200,  p.ct[1] + (size_t)b * 3200,  tid, lane, bx, gx, Tb, xpre, cntb, selb, ltmask);
    compact_level< 200,  16000, 16000>(p.lg[2] + (size_t)b * NC * 800,   p.ct[2] + (size_t)b * 800,   tid, lane, bx, gx, Tb, xpre, cntb, selb, ltmask);
    compact_level<  52,   4160, 16800>(p.lg[3] + (size_t)b * NC * 208,   p.ct[3] + (size_t)b * 208,   tid, lane, bx, gx, Tb, xpre, cntb, selb, ltmask);
    compact_level<  14,   1120, 17008>(p.lg[4] + (size_t)b * NC * 56,    p.ct[4] + (size_t)b * 56,    tid, lane, bx, gx, Tb, xpre, cntb, selb, ltmask);
}

// ---------------- fused select(sort) + decode + greedy NMS ------------------
// 1024 threads, one block per batch. Phase 1: adaptive bitonic sort of the
// <=CAP candidate keys (desc; key=(score_bits<<32)|~idx gives exact lax.top_k
// order: value desc, index asc). Phase 2: candidate r=tid lives in REGISTERS;
// per-iteration argmax == min alive rank == one ballot+ctz per wave.
__global__ void __launch_bounds__(1024) k_selnms(Ptrs p, const unsigned* cnt,
                                                 const unsigned long long* sel,
                                                 const float* im_info, float* out) {
    __shared__ unsigned long long keys[CAP];   // 32 KiB
    __shared__ unsigned wmin[16];
    __shared__ float4 s_pb;
    __shared__ float s_pa;
    int b = blockIdx.x, tid = threadIdx.x;
    int lane = tid & 63, wv = tid >> 6;

    unsigned M = cnt[(size_t)b * CNTSTRIDE];
    if (M > CAP) M = CAP;
    for (int i = tid; i < CAP; i += 1024)
        keys[i] = (i < (int)M) ? sel[(size_t)b * CAP + i] : 0ULL;
    __syncthreads();

    int NS = 1024;                       // pads (0) sort last; M >= TOPK by construction
    while (NS < (int)M) NS <<= 1;
    for (int k = 2; k <= NS; k <<= 1) {
        for (int j = k >> 1; j > 0; j >>= 1) {
            for (int i = tid; i < NS; i += 1024) {
                int ixj = i ^ j;
                if (ixj > i) {
                    unsigned long long va = keys[i], vb = keys[ixj];
                    bool desc = ((i & k) == 0);
                    if (desc ? (va < vb) : (va > vb)) { keys[i] = vb; keys[ixj] = va; }
                }
            }
            __syncthreads();
        }
    }

    // decode candidate rank=tid into registers
    float Him = im_info[b * 2 + 0], Wim = im_info[b * 2 + 1];
    float xmax = Wim - 1.0f, ymax = Him - 1.0f;
    bool alive = false;
    float4 nb = make_float4(0.f, 0.f, 0.f, 0.f);
    float area = 0.f, score = 0.f, clsv = 0.f;
    float4 ob = make_float4(0.f, 0.f, 0.f, 0.f);
    if (tid < TOPK) {
        unsigned long long key = keys[tid];
        if (key != 0ULL) {
            alive = true;
            unsigned sb = (unsigned)(key >> 32);
            unsigned idx = 0xFFFFFFFFu - (unsigned)(key & 0xFFFFFFFFu);
            float val = __uint_as_float(sb);
            int n = idx / NC, c = idx - n * NC;
            int l, hw, W, stride, half, HW;
            level_of(n, l, hw, W, stride, half, HW);
            int wx = hw % W, hy = hw / W;
            float locx = (float)(wx * stride + half);
            float locy = (float)(hy * stride + half);
            const float* bb = p.bb[l] + (size_t)b * 4 * HW + hw;
            float r0 = bb[0], r1 = bb[(size_t)HW], r2 = bb[(size_t)2 * HW], r3 = bb[(size_t)3 * HW];
            float x1 = locx - r0, y1 = locy - r1, x2 = locx + r2, y2 = locy + r3;
            x1 = fminf(fmaxf(x1, 0.f), xmax);
            y1 = fminf(fmaxf(y1, 0.f), ymax);
            x2 = fminf(fmaxf(x2, 0.f), xmax);
            y2 = fminf(fmaxf(y2, 0.f), ymax);
            score = sqrtf(val + 1e-12f);
            float off = (float)c * 10000.0f;
            ob = make_float4(x1, y1, x2, y2);
            clsv = (float)c;
            float a0 = x1 + off, a1 = y1 + off, a2 = x2 + off, a3 = y2 + off;
            nb = make_float4(a0, a1, a2, a3);
            area = fmaxf(a2 - a0, 0.f) * fmaxf(a3 - a1, 0.f);
        }
    }
    __syncthreads();

    bool have_pick = false;
    float4 pb = make_float4(0.f, 0.f, 0.f, 0.f);
    float pa = 0.f;
    for (int it = 0; it < MAXDET; ++it) {
        if (have_pick && alive) {
            float xx1 = fmaxf(pb.x, nb.x);
            float yy1 = fmaxf(pb.y, nb.y);
            float xx2 = fminf(pb.z, nb.z);
            float yy2 = fminf(pb.w, nb.w);
            float inter = fmaxf(xx2 - xx1, 0.f) * fmaxf(yy2 - yy1, 0.f);
            float iou = inter / (((pa + area) - inter) + 1e-9f);
            if (iou >= 0.6f) alive = false;
        }
        unsigned long long mk = __ballot(alive);
        if (lane == 0)
            wmin[wv] = mk ? (unsigned)(wv * 64 + __builtin_ctzll(mk)) : 0xFFFFFFFFu;
        __syncthreads();
        unsigned best = wmin[0];
#pragma unroll
        for (int q = 1; q < 16; ++q) best = min(best, wmin[q]);
        float* o6 = out + ((size_t)b * MAXDET + it) * 6;
        if (best == 0xFFFFFFFFu) {
            if (tid == 0) {
                o6[0] = 0.f; o6[1] = 0.f; o6[2] = 0.f;
                o6[3] = 0.f; o6[4] = 0.f; o6[5] = 0.f;
            }
            have_pick = false;
        } else {
            if ((unsigned)tid == best) {
                o6[0] = ob.x; o6[1] = ob.y; o6[2] = ob.z; o6[3] = ob.w;
                o6[4] = score; o6[5] = clsv;
                s_pb = nb; s_pa = area;
                alive = false;              // picked suppresses itself
            }
            have_pick = true;
        }
        __syncthreads();
        if (have_pick) { pb = s_pb; pa = s_pa; }
    }
}

extern "C" void kernel_launch(void* const* d_in, const int* in_sizes, int n_in,
                              void* d_out, int out_size, void* d_ws, size_t ws_size,
                              hipStream_t stream) {
    Ptrs p;
    for (int l = 0; l < 5; ++l) {
        p.lg[l] = (const float*)d_in[3 * l + 0];
        p.bb[l] = (const float*)d_in[3 * l + 1];
        p.ct[l] = (const float*)d_in[3 * l + 2];
    }
    const float* im_info = (const float*)d_in[15];
    float* out = (float*)d_out;

    unsigned char* w = (unsigned char*)d_ws;
    // layout: [hist 4*16*32KB = 2 MiB | cnt2 16*256B | T 256B] zeroed, then sel
    unsigned* hist           = (unsigned*)(w);                    // 2097152 B
    unsigned* cnt2           = (unsigned*)(w + 2097152);          // 4096 B (padded)
    unsigned* T              = (unsigned*)(w + 2101248);          // 256 B
    unsigned long long* sel  = (unsigned long long*)(w + 2101504); // 16*4096*8

    hipMemsetAsync(w, 0, 2101248, stream);

    k_histA<<<dim3(64, NB), 256, 0, stream>>>(p, hist);
    k_thresh<<<NB, 1024, 0, stream>>>(hist, T);
    k_compactB<<<dim3(128, NB), 256, 0, stream>>>(p, T, cnt2, sel);
    k_selnms<<<NB, 1024, 0, stream>>>(p, cnt2, sel, im_info, out);
}